// Round 11
// baseline (6267.230 us; speedup 1.0000x reference)
//
#include <hip/hip_runtime.h>
#include <hip/hip_bf16.h>

// Problem dims
#define TT 512
#define BB 128
#define DD 1024
#define HH 1024
#define NG 4096    // 4*HH gate columns
#define KT 2048    // DD+HH

using bf8    = __attribute__((ext_vector_type(8))) short;   // 8 bf16 bit patterns
using f32x4  = __attribute__((ext_vector_type(4))) float;
using f32x16 = __attribute__((ext_vector_type(16))) float;

__device__ __forceinline__ unsigned short f2bf(float f) {
  unsigned int u = __builtin_bit_cast(unsigned int, f);
  u += 0x7fffu + ((u >> 16) & 1u);   // RNE
  return (unsigned short)(u >> 16);
}
__device__ __forceinline__ float bf2f(unsigned short u) {
  unsigned int x = ((unsigned int)u) << 16;
  return __builtin_bit_cast(float, x);
}
__device__ __forceinline__ float sigm(float x) { return 1.0f / (1.0f + __expf(-x)); }
__device__ __forceinline__ float ftanh(float x) {
  float e = __expf(2.0f * x);
  return 1.0f - 2.0f / (e + 1.0f);
}

// ---------------- prep kernels ----------------

__global__ void k_detect(const unsigned int* __restrict__ rw, int* __restrict__ flagmode,
                         unsigned int* __restrict__ flags) {
  __shared__ int any;
  if (threadIdx.x == 0) any = 0;
  __syncthreads();
  int loc = 0;
  for (int i = threadIdx.x; i < (TT * BB) / 4; i += blockDim.x)
    if (rw[i] > 1u) loc = 1;
  if (loc) atomicOr(&any, 1);
  __syncthreads();
  if (threadIdx.x == 0) *flagmode = any;
  flags[threadIdx.x] = 1u;   // all 256 producer flags: h-input for step 0 ready
}

// Pack W = [Wx; Wh] (KT x NG, f32 row-major) into Wp[n][k] bf16 (N-major).
__global__ void k_pack(const float* __restrict__ Wx, const float* __restrict__ Wh,
                       unsigned short* __restrict__ Wp) {
  __shared__ unsigned short tile[64][65];
  const int kt = blockIdx.x & 31;
  const int nt = blockIdx.x >> 5;
  const int k0 = kt * 64, n0 = nt * 64;
  const int t = threadIdx.x;
  {
    const int kl = t >> 2;
    const int nl = (t & 3) * 16;
    const int kg = k0 + kl;
    const float* src = (kg < DD) ? (Wx + (size_t)kg * NG + n0 + nl)
                                 : (Wh + (size_t)(kg - DD) * NG + n0 + nl);
#pragma unroll
    for (int j = 0; j < 16; ++j) tile[kl][nl + j] = f2bf(src[j]);
  }
  __syncthreads();
  {
    const int nl = t >> 2;
    const int kl = (t & 3) * 16;
    unsigned short* dst = Wp + (size_t)(n0 + nl) * KT + k0 + kl;
#pragma unroll
    for (int j = 0; j < 16; ++j) dst[j] = tile[kl + j][nl];
  }
}

// staged-layout hbufB init: per group [ci 0..63][lhi 0..1][row32][8]
__global__ void k_initB3(const float* __restrict__ h0, const unsigned char* __restrict__ rB,
                         const int* __restrict__ rI, const int* __restrict__ flagmode,
                         unsigned short* __restrict__ hbufB) {
  const int i = blockIdx.x * 256 + threadIdx.x;
  if (i >= BB * HH) return;
  const int row = i >> 10, hcol = i & 1023;
  const bool r = (*flagmode) ? (rB[row] != 0) : (rI[row] != 0);
  const unsigned short val = r ? (unsigned short)0 : f2bf(h0[i]);
  const int g = row >> 5, rl = row & 31;
  const size_t e = (size_t)g * 32768 + (size_t)(hcol >> 4) * 512
                 + (size_t)((hcol >> 3) & 1) * 256 + (size_t)rl * 8 + (hcol & 7);
  hbufB[e] = val;
}

// obs f32 -> bf16
__global__ void k_cvt(const float* __restrict__ src, unsigned short* __restrict__ dst) {
  size_t i = ((size_t)blockIdx.x * 256 + threadIdx.x) * 8;
  const size_t stride = (size_t)2048 * 256 * 8;
  for (; i < (size_t)TT * BB * DD; i += stride) {
    f32x4 a = *(const f32x4*)(src + i);
    f32x4 c = *(const f32x4*)(src + i + 4);
    uint4 cv;
    asm("v_cvt_pk_bf16_f32 %0, %1, %2" : "=v"(cv.x) : "v"(a[0]), "v"(a[1]));
    asm("v_cvt_pk_bf16_f32 %0, %1, %2" : "=v"(cv.y) : "v"(a[2]), "v"(a[3]));
    asm("v_cvt_pk_bf16_f32 %0, %1, %2" : "=v"(cv.z) : "v"(c[0]), "v"(c[1]));
    asm("v_cvt_pk_bf16_f32 %0, %1, %2" : "=v"(cv.w) : "v"(c[2]), "v"(c[3]));
    *(bf8*)(dst + i) = __builtin_bit_cast(bf8, cv);
  }
}

// ---------------- gx = obs_bf @ Wx  (round-8 proven form, swizzle reverted) ----------------
#define GEMM_SMEM 69632

__global__ void __launch_bounds__(256)
k_gemm(const unsigned short* __restrict__ A, const unsigned short* __restrict__ Bw,
       unsigned short* __restrict__ C) {
  extern __shared__ char gsm[];
  const int tid = threadIdx.x;
  const int w = tid >> 6, l = tid & 63;
  const int l15 = l & 15, lh4 = l >> 4;
  const int wm2 = w >> 1, wn2 = w & 1;
  const int mt = blockIdx.x >> 5, nt = blockIdx.x & 31;
  const size_t m0 = (size_t)mt * 128, n0 = (size_t)nt * 128;

  f32x4 acc[4][4] = {};

  const int srow = l >> 3;
  const int schunk = (l & 7) ^ srow;

  const unsigned short* Ag[4];
  const unsigned short* Bg[4];
#pragma unroll
  for (int i = 0; i < 4; ++i) {
    const int r = w * 32 + i * 8 + srow;
    Ag[i] = A + (m0 + r) * 1024 + schunk * 8;
    Bg[i] = Bw + (n0 + r) * 2048 + schunk * 8;
  }

#define GSTAGE(BUF, KS) do {                                                        \
    const size_t ko_ = (size_t)(KS) * 64;                                           \
    char* base_ = gsm + (BUF) * 32768;                                              \
    _Pragma("unroll")                                                               \
    for (int i_ = 0; i_ < 4; ++i_) {                                                \
      __builtin_amdgcn_global_load_lds(                                             \
        (const __attribute__((address_space(1))) unsigned int*)(Ag[i_] + ko_),      \
        (__attribute__((address_space(3))) unsigned int*)(base_ + (w*32 + i_*8)*128), \
        16, 0, 0);                                                                  \
      __builtin_amdgcn_global_load_lds(                                             \
        (const __attribute__((address_space(1))) unsigned int*)(Bg[i_] + ko_),      \
        (__attribute__((address_space(3))) unsigned int*)(base_ + 16384 + (w*32 + i_*8)*128), \
        16, 0, 0);                                                                  \
    }                                                                               \
  } while (0)

#define GCOMP(BUF) do {                                                             \
    const char* bA_ = gsm + (BUF) * 32768;                                          \
    const char* bB_ = bA_ + 16384;                                                  \
    _Pragma("unroll")                                                               \
    for (int kk_ = 0; kk_ < 2; ++kk_) {                                             \
      bf8 af_[4], bf_[4];                                                           \
      _Pragma("unroll")                                                             \
      for (int mi_ = 0; mi_ < 4; ++mi_) {                                           \
        const int r_ = wm2 * 64 + mi_ * 16 + l15;                                   \
        af_[mi_] = *(const bf8*)(bA_ + r_ * 128 + ((kk_*64 + lh4*16) ^ ((r_ & 7) << 4))); \
      }                                                                             \
      _Pragma("unroll")                                                             \
      for (int ni_ = 0; ni_ < 4; ++ni_) {                                           \
        const int r_ = wn2 * 64 + ni_ * 16 + l15;                                   \
        bf_[ni_] = *(const bf8*)(bB_ + r_ * 128 + ((kk_*64 + lh4*16) ^ ((r_ & 7) << 4))); \
      }                                                                             \
      _Pragma("unroll")                                                             \
      for (int mi_ = 0; mi_ < 4; ++mi_)                                             \
        _Pragma("unroll")                                                           \
        for (int ni_ = 0; ni_ < 4; ++ni_)                                           \
          acc[mi_][ni_] = __builtin_amdgcn_mfma_f32_16x16x32_bf16(                  \
              af_[mi_], bf_[ni_], acc[mi_][ni_], 0, 0, 0);                          \
    }                                                                               \
  } while (0)

  GSTAGE(0, 0);
  asm volatile("s_waitcnt vmcnt(0)" ::: "memory");
  __syncthreads();
#pragma unroll 1
  for (int ks = 0; ks < 16; ++ks) {
    if (ks < 15) GSTAGE((ks + 1) & 1, ks + 1);
    GCOMP(ks & 1);
    if (ks < 15) {
      asm volatile("s_waitcnt vmcnt(0)" ::: "memory");
      __syncthreads();
    }
  }

  __syncthreads();
  float* ct = (float*)(gsm + w * 17408);   // [64][68] f32
#pragma unroll
  for (int mi = 0; mi < 4; ++mi)
#pragma unroll
    for (int ni = 0; ni < 4; ++ni)
#pragma unroll
      for (int q = 0; q < 4; ++q)
        ct[(mi * 16 + lh4 * 4 + q) * 68 + ni * 16 + l15] = acc[mi][ni][q];
#pragma unroll
  for (int i = 0; i < 8; ++i) {
    const int row = i * 8 + (l >> 3);
    const int c8 = (l & 7) * 8;
    f32x4 v0 = *(const f32x4*)(ct + row * 68 + c8);
    f32x4 v1 = *(const f32x4*)(ct + row * 68 + c8 + 4);
    uint4 cv;
    asm("v_cvt_pk_bf16_f32 %0, %1, %2" : "=v"(cv.x) : "v"(v0[0]), "v"(v0[1]));
    asm("v_cvt_pk_bf16_f32 %0, %1, %2" : "=v"(cv.y) : "v"(v0[2]), "v"(v0[3]));
    asm("v_cvt_pk_bf16_f32 %0, %1, %2" : "=v"(cv.z) : "v"(v1[0]), "v"(v1[1]));
    asm("v_cvt_pk_bf16_f32 %0, %1, %2" : "=v"(cv.w) : "v"(v1[2]), "v"(v1[3]));
    *(bf8*)(C + (m0 + wm2 * 64 + row) * 4096 + n0 + wn2 * 64 + c8) =
        __builtin_bit_cast(bf8, cv);
  }
#undef GSTAGE
#undef GCOMP
}

// ---------------- serial h-scan v5: L2-cached h reads + acquire-invalidate ----------------
// LDS: Wl [k8 0..127][c 0..63][16B] @0 (131072); TMP 3x8KB @131072; GL [32][66] f32 aliases
#define SCANH_SMEM 155648
#define TMP_OFF 131072
#define HSLOT3 262144   // 4 groups * 64KB per hbufB slot

// PLAIN cached load (through L1/L2): freshness guaranteed by the acquire fence
// (L1/L2 invalidate) executed after the poll each step. Publishes are sc0 sc1
// (write to LLC), so post-invalidate refills are fresh; same-XCD blocks share L2 fills.
#define HI3(I) asm volatile("global_load_dwordx4 %0, %1, off" \
    : "=v"(ha[I]) : "v"(hbB + (I) * 1024) : "memory")

// B fragment: global k16-chunk CI, col-tile CN: Wl[(CI*2+lhi)][CN*32+l31]
#define BRD3(CI, CN) (*(const bf8*)(sm + \
    (size_t)((((CI) * 2 + lhi) * 64 + (CN) * 32 + l31)) * 16))

// Counted vmcnt is E-robust: h-loads are the newest 16 outstanding vmem ops.
#define HC3(CI, VM) do {                                                  \
    bf8 nb0, nb1;                                                         \
    if ((CI) < 15) { nb0 = BRD3(kc0 + (CI) + 1, 0); nb1 = BRD3(kc0 + (CI) + 1, 1); } \
    asm volatile("s_waitcnt vmcnt(" #VM ")" ::: "memory");                \
    __builtin_amdgcn_sched_barrier(0);                                    \
    ac0 = __builtin_amdgcn_mfma_f32_32x32x16_bf16(ha[CI], cb0, ac0, 0, 0, 0); \
    ac1 = __builtin_amdgcn_mfma_f32_32x32x16_bf16(ha[CI], cb1, ac1, 0, 0, 0); \
    cb0 = nb0; cb1 = nb1;                                                 \
  } while (0)

__global__ void __launch_bounds__(256)
k_scanh(const unsigned char* __restrict__ resetsB, const int* __restrict__ resetsI,
        const float* __restrict__ c0, const float* __restrict__ bias,
        const unsigned short* __restrict__ Wp, const unsigned short* __restrict__ gx,
        unsigned short* __restrict__ hbufB, unsigned int* __restrict__ flags,
        const int* __restrict__ flagmode, float* __restrict__ out) {
  extern __shared__ char sm[];
  float* TG = (float*)(sm + TMP_OFF);

  const int tid = threadIdx.x;
  const int wq  = tid >> 6;
  const int ln  = tid & 63;
  const int l31 = ln & 31;
  const int lhi = ln >> 5;
  const int kc0 = wq * 16;
  const int bid = blockIdx.x;
  const int g   = bid >> 6;        // batch group 0..3 (rows 32g..32g+31)
  const int b   = bid & 63;        // 16 h-cols per block
  const int byteMode = *flagmode;

  // ---- Wl slice -> LDS (once): [k8][c][8], c = gate*16 + hcl ----
  {
    const int c = tid >> 2, seg = tid & 3;
    const int n = (c >> 4) * 1024 + b * 16 + (c & 15);
    const unsigned short* src = Wp + (size_t)n * KT + 1024;
#pragma unroll 8
    for (int i = 0; i < 32; ++i) {
      const int k8 = seg * 32 + i;
      bf8 v = *(const bf8*)(src + k8 * 8);
      *(bf8*)(sm + ((size_t)k8 * 64 + c) * 16) = v;
    }
  }

  const int row  = tid >> 3;           // 0..31
  const int jd   = tid & 7;
  const int grow = g * 32 + row;
  const int hc   = b * 16 + jd * 2;

  float ccx = c0[(size_t)grow * HH + hc];
  float ccy = c0[(size_t)grow * HH + hc + 1];
  const float bx0 = bias[0 * HH + hc], by0 = bias[0 * HH + hc + 1];
  const float bx1 = bias[1 * HH + hc], by1 = bias[1 * HH + hc + 1];
  const float bx2 = bias[2 * HH + hc], by2 = bias[2 * HH + hc + 1];
  const float bx3 = bias[3 * HH + hc], by3 = bias[3 * HH + hc + 1];

  const size_t puboff = (size_t)(hc >> 4) * 1024 + (size_t)((hc >> 3) & 1) * 512
                      + (size_t)row * 16 + (size_t)(hc & 7) * 2;

  __syncthreads();   // Wl ready

#pragma unroll 1
  for (int t = 0; t < TT; ++t) {
    // ---- prefetch gx (4x4B) + resets before the poll ----
    const unsigned short* gp = gx + ((size_t)t * BB + grow) * 4096 + hc;
    const unsigned int gx0 = *(const unsigned int*)(gp);
    const unsigned int gx1 = *(const unsigned int*)(gp + 1024);
    const unsigned int gx2 = *(const unsigned int*)(gp + 2048);
    const unsigned int gx3 = *(const unsigned int*)(gp + 3072);
    bool rc, rn = false;
    if (byteMode) {
      rc = resetsB[t * BB + grow] != 0;
      if (t + 1 < TT) rn = resetsB[(t + 1) * BB + grow] != 0;
    } else {
      rc = resetsI[t * BB + grow] != 0;
      if (t + 1 < TT) rn = resetsI[(t + 1) * BB + grow] != 0;
    }

    // ---- poll own group's 64 producer flags (relaxed agent loads) ----
    {
      const unsigned int need = (unsigned int)(t + 1);
      const unsigned int* fp = flags + g * 64;
      while (true) {
        unsigned int v = __hip_atomic_load(&fp[ln], __ATOMIC_RELAXED,
                                           __HIP_MEMORY_SCOPE_AGENT);
        if (__all(v >= need)) break;
        __builtin_amdgcn_s_sleep(2);
      }
    }
    // Acquire at agent scope: invalidates L1 + (non-local) L2 lines so the
    // PLAIN h loads below observe the producers' LLC publishes, and refills
    // are L2-cached / shared across this XCD's blocks.
    __builtin_amdgcn_fence(__ATOMIC_ACQUIRE, "agent");
    __builtin_amdgcn_sched_barrier(0);

    // ---- h MFMA phase: 16 cached A-loads, counted vmcnt ----
    f32x16 ac0 = {0.f,0.f,0.f,0.f, 0.f,0.f,0.f,0.f, 0.f,0.f,0.f,0.f, 0.f,0.f,0.f,0.f};
    f32x16 ac1 = {0.f,0.f,0.f,0.f, 0.f,0.f,0.f,0.f, 0.f,0.f,0.f,0.f, 0.f,0.f,0.f,0.f};
    {
      const char* hbB = (const char*)hbufB + (size_t)(t & 1) * HSLOT3
                      + (size_t)g * 65536 + (size_t)kc0 * 1024
                      + (size_t)lhi * 512 + (size_t)l31 * 16;
      bf8 ha[16];
      HI3(0);  HI3(1);  HI3(2);  HI3(3);  HI3(4);  HI3(5);  HI3(6);  HI3(7);
      HI3(8);  HI3(9);  HI3(10); HI3(11); HI3(12); HI3(13); HI3(14); HI3(15);
      bf8 cb0 = BRD3(kc0, 0), cb1 = BRD3(kc0, 1);
      HC3(0, 15);  HC3(1, 14);  HC3(2, 13);  HC3(3, 12);
      HC3(4, 11);  HC3(5, 10);  HC3(6, 9);   HC3(7, 8);
      HC3(8, 7);   HC3(9, 6);   HC3(10, 5);  HC3(11, 4);
      HC3(12, 3);  HC3(13, 2);  HC3(14, 1);  HC3(15, 0);
    }

    // ---- 4-way K combine: waves 1..3 dump to TMP; wq0 accumulates + writes GL
    //      (wq0's TMP reads -> GL writes are same-wave ordered: 2 barriers total)
    if (wq > 0) {
      char* tp = sm + TMP_OFF + (wq - 1) * 8192 + ln * 16;
#pragma unroll
      for (int qd = 0; qd < 4; ++qd) {
        f32x4 v0 = {ac0[qd*4+0], ac0[qd*4+1], ac0[qd*4+2], ac0[qd*4+3]};
        f32x4 v1 = {ac1[qd*4+0], ac1[qd*4+1], ac1[qd*4+2], ac1[qd*4+3]};
        *(f32x4*)(tp + qd * 1024)        = v0;
        *(f32x4*)(tp + 4096 + qd * 1024) = v1;
      }
    }
    __syncthreads();   // TMP dumped
    if (wq == 0) {
#pragma unroll
      for (int s = 0; s < 3; ++s) {
        const char* tp = sm + TMP_OFF + s * 8192 + ln * 16;
#pragma unroll
        for (int qd = 0; qd < 4; ++qd) {
          f32x4 v0 = *(const f32x4*)(tp + qd * 1024);
          f32x4 v1 = *(const f32x4*)(tp + 4096 + qd * 1024);
          ac0[qd*4+0] += v0[0]; ac0[qd*4+1] += v0[1];
          ac0[qd*4+2] += v0[2]; ac0[qd*4+3] += v0[3];
          ac1[qd*4+0] += v1[0]; ac1[qd*4+1] += v1[1];
          ac1[qd*4+2] += v1[2]; ac1[qd*4+3] += v1[3];
        }
      }
      // D layout 32x32: col = lane&31, row = (reg&3) + 8*(reg>>2) + 4*(lane>>5)
#pragma unroll
      for (int r = 0; r < 16; ++r) {
        const int rowl = (r & 3) + 8 * (r >> 2) + 4 * lhi;
        TG[rowl * 66 + l31]      = ac0[r];
        TG[rowl * 66 + 32 + l31] = ac1[r];
      }
    }
    __syncthreads();   // GL ready

    // ---- elementwise LSTM: 2 cells per thread ----
    const float* GLr = TG + row * 66;
    const int hl = jd * 2;
    const float i0 = GLr[ 0 + hl]     + bf2f((unsigned short)(gx0 & 0xffff)) + bx0;
    const float i1 = GLr[ 0 + hl + 1] + bf2f((unsigned short)(gx0 >> 16))    + by0;
    const float f0 = GLr[16 + hl]     + bf2f((unsigned short)(gx1 & 0xffff)) + bx1;
    const float f1 = GLr[16 + hl + 1] + bf2f((unsigned short)(gx1 >> 16))    + by1;
    const float g0 = GLr[32 + hl]     + bf2f((unsigned short)(gx2 & 0xffff)) + bx2;
    const float g1 = GLr[32 + hl + 1] + bf2f((unsigned short)(gx2 >> 16))    + by2;
    const float o0 = GLr[48 + hl]     + bf2f((unsigned short)(gx3 & 0xffff)) + bx3;
    const float o1 = GLr[48 + hl + 1] + bf2f((unsigned short)(gx3 >> 16))    + by3;
    const float cox = rc ? 0.f : ccx;
    const float coy = rc ? 0.f : ccy;
    const float ncx = sigm(f0) * cox + sigm(i0) * ftanh(g0);
    const float ncy = sigm(f1) * coy + sigm(i1) * ftanh(g1);
    const float nhx = sigm(o0) * ftanh(ncx);
    const float nhy = sigm(o1) * ftanh(ncy);
    ccx = ncx; ccy = ncy;

    // ---- publish h (4B coherent store to LLC) + flag, then out stores ----
    if (t + 1 < TT) {
      const float hx = rn ? 0.f : nhx, hy = rn ? 0.f : nhy;
      unsigned int hp;
      asm("v_cvt_pk_bf16_f32 %0, %1, %2" : "=v"(hp) : "v"(hx), "v"(hy));
      char* dst = (char*)hbufB + (size_t)((t + 1) & 1) * HSLOT3
                + (size_t)g * 65536 + puboff;
      asm volatile("global_store_dword %0, %1, off sc0 sc1" :: "v"(dst), "v"(hp) : "memory");
      asm volatile("s_waitcnt vmcnt(0)" ::: "memory");
      __syncthreads();
      if (tid == 0) {
        unsigned int* fp = flags + bid;
        const unsigned int val = (unsigned int)(t + 2);
        asm volatile("global_store_dword %0, %1, off sc0 sc1" :: "v"(fp), "v"(val) : "memory");
      }
      float* op = out + (size_t)t * BB * HH + (size_t)grow * HH + hc;
      op[0] = nhx; op[1] = nhy;
    } else {
      float* op = out + (size_t)t * BB * HH + (size_t)grow * HH + hc;
      op[0] = nhx; op[1] = nhy;
      float* hp2 = out + (size_t)TT * BB * HH + (size_t)grow * HH + hc;
      hp2[0] = nhx; hp2[1] = nhy;
      float* cp2 = out + (size_t)TT * BB * HH + (size_t)BB * HH + (size_t)grow * HH + hc;
      cp2[0] = ncx; cp2[1] = ncy;
    }
  }
}

// ---------------- launch ----------------

extern "C" void kernel_launch(void* const* d_in, const int* in_sizes, int n_in,
                              void* d_out, int out_size, void* d_ws, size_t ws_size,
                              hipStream_t stream) {
  const float* obs  = (const float*)d_in[0];
  const void*  rst  = d_in[1];
  const float* h0   = (const float*)d_in[2];
  const float* c0   = (const float*)d_in[3];
  const float* Wx   = (const float*)d_in[4];
  const float* Wh   = (const float*)d_in[5];
  const float* bias = (const float*)d_in[6];
  float* out = (float*)d_out;

  char* ws = (char*)d_ws;
  const size_t WP_OFF    = 0;                                   // 16 MiB
  const size_t FLAGS_OFF = ((size_t)16 << 20) + ((size_t)512 << 10);
  const size_t HBUFB_OFF = (size_t)17 << 20;                    // 0.5 MiB (staged layout)
  const size_t OBSBF_OFF = (size_t)24 << 20;                    // 128 MiB
  const size_t GX_OFF    = OBSBF_OFF + ((size_t)128 << 20);     // 512 MiB

  unsigned short* Wp    = (unsigned short*)(ws + WP_OFF);
  unsigned int*   flags = (unsigned int*)(ws + FLAGS_OFF);
  int*        flagmode  = (int*)(flags + 1024);
  unsigned short* hbufB = (unsigned short*)(ws + HBUFB_OFF);
  unsigned short* obsbf = (unsigned short*)(ws + OBSBF_OFF);
  unsigned short* gxp   = (unsigned short*)(ws + GX_OFF);

  const unsigned char* rB = (const unsigned char*)rst;
  const int* rI = (const int*)rst;

  k_detect<<<1, 256, 0, stream>>>((const unsigned int*)rst, flagmode, flags);
  k_pack<<<dim3((KT / 64) * (NG / 64)), dim3(256), 0, stream>>>(Wx, Wh, Wp);
  k_initB3<<<dim3((BB * HH) / 256), dim3(256), 0, stream>>>(h0, rB, rI, flagmode, hbufB);
  k_cvt<<<dim3(2048), dim3(256), 0, stream>>>(obs, obsbf);
  hipFuncSetAttribute((const void*)k_gemm,
                      hipFuncAttributeMaxDynamicSharedMemorySize, GEMM_SMEM);
  k_gemm<<<dim3((TT * BB / 128) * (NG / 128)), dim3(256), GEMM_SMEM, stream>>>(
      obsbf, Wp, gxp);

  hipFuncSetAttribute((const void*)k_scanh,
                      hipFuncAttributeMaxDynamicSharedMemorySize, SCANH_SMEM);
  void* args3[] = { (void*)&rB, (void*)&rI, (void*)&c0, (void*)&bias, (void*)&Wp,
                    (void*)&gxp, (void*)&hbufB, (void*)&flags, (void*)&flagmode,
                    (void*)&out };
  hipLaunchCooperativeKernel((const void*)k_scanh, dim3(256), dim3(256), args3,
                             SCANH_SMEM, stream);
}

// Round 13
// 2803.908 us; speedup vs baseline: 2.2352x; 2.2352x over previous
//
#include <hip/hip_runtime.h>
#include <hip/hip_bf16.h>

// Problem dims
#define TT 512
#define BB 128
#define DD 1024
#define HH 1024
#define NG 4096    // 4*HH gate columns
#define KT 2048    // DD+HH

using bf8    = __attribute__((ext_vector_type(8))) short;   // 8 bf16 bit patterns
using u32x2  = __attribute__((ext_vector_type(2))) unsigned int;
using f32x4  = __attribute__((ext_vector_type(4))) float;
using f32x16 = __attribute__((ext_vector_type(16))) float;

__device__ __forceinline__ unsigned short f2bf(float f) {
  unsigned int u = __builtin_bit_cast(unsigned int, f);
  u += 0x7fffu + ((u >> 16) & 1u);   // RNE
  return (unsigned short)(u >> 16);
}
__device__ __forceinline__ float bf2f(unsigned short u) {
  unsigned int x = ((unsigned int)u) << 16;
  return __builtin_bit_cast(float, x);
}
__device__ __forceinline__ float sigm(float x) { return 1.0f / (1.0f + __expf(-x)); }
__device__ __forceinline__ float ftanh(float x) {
  float e = __expf(2.0f * x);
  return 1.0f - 2.0f / (e + 1.0f);
}

// 8 int8 bytes -> 8 bf16 (values are small ints: i8->f32->bf16 all exact)
__device__ __forceinline__ bf8 i8x8_to_bf16x8(u32x2 v) {
  const int d0 = (int)v[0], d1 = (int)v[1];
  const float f0 = (float)((d0 << 24) >> 24);
  const float f1 = (float)((d0 << 16) >> 24);
  const float f2 = (float)((d0 <<  8) >> 24);
  const float f3 = (float)( d0        >> 24);
  const float f4 = (float)((d1 << 24) >> 24);
  const float f5 = (float)((d1 << 16) >> 24);
  const float f6 = (float)((d1 <<  8) >> 24);
  const float f7 = (float)( d1        >> 24);
  uint4 cv;
  asm("v_cvt_pk_bf16_f32 %0, %1, %2" : "=v"(cv.x) : "v"(f0), "v"(f1));
  asm("v_cvt_pk_bf16_f32 %0, %1, %2" : "=v"(cv.y) : "v"(f2), "v"(f3));
  asm("v_cvt_pk_bf16_f32 %0, %1, %2" : "=v"(cv.z) : "v"(f4), "v"(f5));
  asm("v_cvt_pk_bf16_f32 %0, %1, %2" : "=v"(cv.w) : "v"(f6), "v"(f7));
  return __builtin_bit_cast(bf8, cv);
}

// ---------------- prep kernels ----------------

__global__ void k_detect(const unsigned int* __restrict__ rw, int* __restrict__ flagmode,
                         unsigned int* __restrict__ flags) {
  __shared__ int any;
  if (threadIdx.x == 0) any = 0;
  __syncthreads();
  int loc = 0;
  for (int i = threadIdx.x; i < (TT * BB) / 4; i += blockDim.x)
    if (rw[i] > 1u) loc = 1;
  if (loc) atomicOr(&any, 1);
  __syncthreads();
  if (threadIdx.x == 0) *flagmode = any;
  flags[threadIdx.x] = 1u;   // 256 producer flags: h-input for step 0 ready
}

// Pack W = [Wx; Wh] (KT x NG, f32 row-major) into Wp[n][k] bf16 (N-major).
__global__ void k_pack(const float* __restrict__ Wx, const float* __restrict__ Wh,
                       unsigned short* __restrict__ Wp) {
  __shared__ unsigned short tile[64][65];
  const int kt = blockIdx.x & 31;
  const int nt = blockIdx.x >> 5;
  const int k0 = kt * 64, n0 = nt * 64;
  const int t = threadIdx.x;
  {
    const int kl = t >> 2;
    const int nl = (t & 3) * 16;
    const int kg = k0 + kl;
    const float* src = (kg < DD) ? (Wx + (size_t)kg * NG + n0 + nl)
                                 : (Wh + (size_t)(kg - DD) * NG + n0 + nl);
#pragma unroll
    for (int j = 0; j < 16; ++j) tile[kl][nl + j] = f2bf(src[j]);
  }
  __syncthreads();
  {
    const int nl = t >> 2;
    const int kl = (t & 3) * 16;
    unsigned short* dst = Wp + (size_t)(n0 + nl) * KT + k0 + kl;
#pragma unroll
    for (int j = 0; j < 16; ++j) dst[j] = tile[kl + j][nl];
  }
}

// bf16 h0 staged layout (t==0 reads): per group [ci 0..63][lhi 0..1][row32][8]
__global__ void k_initB3(const float* __restrict__ h0, const unsigned char* __restrict__ rB,
                         const int* __restrict__ rI, const int* __restrict__ flagmode,
                         unsigned short* __restrict__ hbufB16) {
  const int i = blockIdx.x * 256 + threadIdx.x;
  if (i >= BB * HH) return;
  const int row = i >> 10, hcol = i & 1023;
  const bool r = (*flagmode) ? (rB[row] != 0) : (rI[row] != 0);
  const unsigned short val = r ? (unsigned short)0 : f2bf(h0[i]);
  const int g = row >> 5, rl = row & 31;
  const size_t e = (size_t)g * 32768 + (size_t)(hcol >> 4) * 512
                 + (size_t)((hcol >> 3) & 1) * 256 + (size_t)rl * 8 + (hcol & 7);
  hbufB16[e] = val;
}

// obs f32 -> bf16
__global__ void k_cvt(const float* __restrict__ src, unsigned short* __restrict__ dst) {
  size_t i = ((size_t)blockIdx.x * 256 + threadIdx.x) * 8;
  const size_t stride = (size_t)2048 * 256 * 8;
  for (; i < (size_t)TT * BB * DD; i += stride) {
    f32x4 a = *(const f32x4*)(src + i);
    f32x4 c = *(const f32x4*)(src + i + 4);
    uint4 cv;
    asm("v_cvt_pk_bf16_f32 %0, %1, %2" : "=v"(cv.x) : "v"(a[0]), "v"(a[1]));
    asm("v_cvt_pk_bf16_f32 %0, %1, %2" : "=v"(cv.y) : "v"(a[2]), "v"(a[3]));
    asm("v_cvt_pk_bf16_f32 %0, %1, %2" : "=v"(cv.z) : "v"(c[0]), "v"(c[1]));
    asm("v_cvt_pk_bf16_f32 %0, %1, %2" : "=v"(cv.w) : "v"(c[2]), "v"(c[3]));
    *(bf8*)(dst + i) = __builtin_bit_cast(bf8, cv);
  }
}

// ---------------- gx = obs_bf @ Wx  (round-8 proven form) ----------------
#define GEMM_SMEM 69632

__global__ void __launch_bounds__(256)
k_gemm(const unsigned short* __restrict__ A, const unsigned short* __restrict__ Bw,
       unsigned short* __restrict__ C) {
  extern __shared__ char gsm[];
  const int tid = threadIdx.x;
  const int w = tid >> 6, l = tid & 63;
  const int l15 = l & 15, lh4 = l >> 4;
  const int wm2 = w >> 1, wn2 = w & 1;
  const int mt = blockIdx.x >> 5, nt = blockIdx.x & 31;
  const size_t m0 = (size_t)mt * 128, n0 = (size_t)nt * 128;

  f32x4 acc[4][4] = {};

  const int srow = l >> 3;
  const int schunk = (l & 7) ^ srow;

  const unsigned short* Ag[4];
  const unsigned short* Bg[4];
#pragma unroll
  for (int i = 0; i < 4; ++i) {
    const int r = w * 32 + i * 8 + srow;
    Ag[i] = A + (m0 + r) * 1024 + schunk * 8;
    Bg[i] = Bw + (n0 + r) * 2048 + schunk * 8;
  }

#define GSTAGE(BUF, KS) do {                                                        \
    const size_t ko_ = (size_t)(KS) * 64;                                           \
    char* base_ = gsm + (BUF) * 32768;                                              \
    _Pragma("unroll")                                                               \
    for (int i_ = 0; i_ < 4; ++i_) {                                                \
      __builtin_amdgcn_global_load_lds(                                             \
        (const __attribute__((address_space(1))) unsigned int*)(Ag[i_] + ko_),      \
        (__attribute__((address_space(3))) unsigned int*)(base_ + (w*32 + i_*8)*128), \
        16, 0, 0);                                                                  \
      __builtin_amdgcn_global_load_lds(                                             \
        (const __attribute__((address_space(1))) unsigned int*)(Bg[i_] + ko_),      \
        (__attribute__((address_space(3))) unsigned int*)(base_ + 16384 + (w*32 + i_*8)*128), \
        16, 0, 0);                                                                  \
    }                                                                               \
  } while (0)

#define GCOMP(BUF) do {                                                             \
    const char* bA_ = gsm + (BUF) * 32768;                                          \
    const char* bB_ = bA_ + 16384;                                                  \
    _Pragma("unroll")                                                               \
    for (int kk_ = 0; kk_ < 2; ++kk_) {                                             \
      bf8 af_[4], bf_[4];                                                           \
      _Pragma("unroll")                                                             \
      for (int mi_ = 0; mi_ < 4; ++mi_) {                                           \
        const int r_ = wm2 * 64 + mi_ * 16 + l15;                                   \
        af_[mi_] = *(const bf8*)(bA_ + r_ * 128 + ((kk_*64 + lh4*16) ^ ((r_ & 7) << 4))); \
      }                                                                             \
      _Pragma("unroll")                                                             \
      for (int ni_ = 0; ni_ < 4; ++ni_) {                                           \
        const int r_ = wn2 * 64 + ni_ * 16 + l15;                                   \
        bf_[ni_] = *(const bf8*)(bB_ + r_ * 128 + ((kk_*64 + lh4*16) ^ ((r_ & 7) << 4))); \
      }                                                                             \
      _Pragma("unroll")                                                             \
      for (int mi_ = 0; mi_ < 4; ++mi_)                                             \
        _Pragma("unroll")                                                           \
        for (int ni_ = 0; ni_ < 4; ++ni_)                                           \
          acc[mi_][ni_] = __builtin_amdgcn_mfma_f32_16x16x32_bf16(                  \
              af_[mi_], bf_[ni_], acc[mi_][ni_], 0, 0, 0);                          \
    }                                                                               \
  } while (0)

  GSTAGE(0, 0);
  asm volatile("s_waitcnt vmcnt(0)" ::: "memory");
  __syncthreads();
#pragma unroll 1
  for (int ks = 0; ks < 16; ++ks) {
    if (ks < 15) GSTAGE((ks + 1) & 1, ks + 1);
    GCOMP(ks & 1);
    if (ks < 15) {
      asm volatile("s_waitcnt vmcnt(0)" ::: "memory");
      __syncthreads();
    }
  }

  __syncthreads();
  float* ct = (float*)(gsm + w * 17408);   // [64][68] f32
#pragma unroll
  for (int mi = 0; mi < 4; ++mi)
#pragma unroll
    for (int ni = 0; ni < 4; ++ni)
#pragma unroll
      for (int q = 0; q < 4; ++q)
        ct[(mi * 16 + lh4 * 4 + q) * 68 + ni * 16 + l15] = acc[mi][ni][q];
#pragma unroll
  for (int i = 0; i < 8; ++i) {
    const int row = i * 8 + (l >> 3);
    const int c8 = (l & 7) * 8;
    f32x4 v0 = *(const f32x4*)(ct + row * 68 + c8);
    f32x4 v1 = *(const f32x4*)(ct + row * 68 + c8 + 4);
    uint4 cv;
    asm("v_cvt_pk_bf16_f32 %0, %1, %2" : "=v"(cv.x) : "v"(v0[0]), "v"(v0[1]));
    asm("v_cvt_pk_bf16_f32 %0, %1, %2" : "=v"(cv.y) : "v"(v0[2]), "v"(v0[3]));
    asm("v_cvt_pk_bf16_f32 %0, %1, %2" : "=v"(cv.z) : "v"(v1[0]), "v"(v1[1]));
    asm("v_cvt_pk_bf16_f32 %0, %1, %2" : "=v"(cv.w) : "v"(v1[2]), "v"(v1[3]));
    *(bf8*)(C + (m0 + wm2 * 64 + row) * 4096 + n0 + wn2 * 64 + c8) =
        __builtin_bit_cast(bf8, cv);
  }
#undef GSTAGE
#undef GCOMP
}

// ---------------- serial h-scan v7: int8 h-state, bf16 step-0 ----------------
// LDS: Wl [k8 0..127][c 0..63][16B] @0 (131072); TMP 3x8KB @131072; GL [32][66] f32 aliases
#define SCANH_SMEM 155648
#define TMP_OFF 131072
#define HSLOTQ 131072   // int8: 4 groups * 32KB per slot

// bf16 (t==0) coherent 16B load
#define HI3(I) asm volatile("global_load_dwordx4 %0, %1, off sc0 sc1" \
    : "=v"(hb16[I]) : "v"(hbB16 + (I) * 1024) : "memory")
// int8 coherent 8B load
#define HIQ(I) asm volatile("global_load_dwordx2 %0, %1, off sc0 sc1" \
    : "=v"(haq[I]) : "v"(hbQ + (I) * 512) : "memory")

// B fragment: global k16-chunk CI, col-tile CN
#define BRD3(CI, CN) (*(const bf8*)(sm + \
    (size_t)((((CI) * 2 + lhi) * 64 + (CN) * 32 + l31)) * 16))

// Counted vmcnt is E-robust: h-loads are the newest 16 outstanding vmem ops.
#define HC3(CI, VM) do {                                                  \
    bf8 nb0, nb1;                                                         \
    if ((CI) < 15) { nb0 = BRD3(kc0 + (CI) + 1, 0); nb1 = BRD3(kc0 + (CI) + 1, 1); } \
    asm volatile("s_waitcnt vmcnt(" #VM ")" ::: "memory");                \
    __builtin_amdgcn_sched_barrier(0);                                    \
    ac0 = __builtin_amdgcn_mfma_f32_32x32x16_bf16(hb16[CI], cb0, ac0, 0, 0, 0); \
    ac1 = __builtin_amdgcn_mfma_f32_32x32x16_bf16(hb16[CI], cb1, ac1, 0, 0, 0); \
    cb0 = nb0; cb1 = nb1;                                                 \
  } while (0)

#define HCQ(CI, VM) do {                                                  \
    bf8 nb0, nb1;                                                         \
    if ((CI) < 15) { nb0 = BRD3(kc0 + (CI) + 1, 0); nb1 = BRD3(kc0 + (CI) + 1, 1); } \
    asm volatile("s_waitcnt vmcnt(" #VM ")" ::: "memory");                \
    __builtin_amdgcn_sched_barrier(0);                                    \
    const bf8 af_ = i8x8_to_bf16x8(haq[CI]);                              \
    ac0 = __builtin_amdgcn_mfma_f32_32x32x16_bf16(af_, cb0, ac0, 0, 0, 0); \
    ac1 = __builtin_amdgcn_mfma_f32_32x32x16_bf16(af_, cb1, ac1, 0, 0, 0); \
    cb0 = nb0; cb1 = nb1;                                                 \
  } while (0)

__global__ void __launch_bounds__(256)
k_scanh(const unsigned char* __restrict__ resetsB, const int* __restrict__ resetsI,
        const float* __restrict__ c0, const float* __restrict__ bias,
        const unsigned short* __restrict__ Wp, const unsigned short* __restrict__ gx,
        const unsigned short* __restrict__ hbufB16, unsigned char* __restrict__ hbufQ,
        unsigned int* __restrict__ flags, const int* __restrict__ flagmode,
        float* __restrict__ out) {
  extern __shared__ char sm[];
  float* TG = (float*)(sm + TMP_OFF);

  const int tid = threadIdx.x;
  const int wq  = tid >> 6;
  const int ln  = tid & 63;
  const int l31 = ln & 31;
  const int lhi = ln >> 5;
  const int kc0 = wq * 16;
  const int bid = blockIdx.x;
  const int g   = bid >> 6;        // batch group 0..3 (rows 32g..32g+31)
  const int b   = bid & 63;        // 16 h-cols per block
  const int byteMode = *flagmode;

  // ---- Wl slice -> LDS (once): [k8][c][8], c = gate*16 + hcl ----
  {
    const int c = tid >> 2, seg = tid & 3;
    const int n = (c >> 4) * 1024 + b * 16 + (c & 15);
    const unsigned short* src = Wp + (size_t)n * KT + 1024;
#pragma unroll 8
    for (int i = 0; i < 32; ++i) {
      const int k8 = seg * 32 + i;
      bf8 v = *(const bf8*)(src + k8 * 8);
      *(bf8*)(sm + ((size_t)k8 * 64 + c) * 16) = v;
    }
  }

  const int row  = tid >> 3;           // 0..31
  const int jd   = tid & 7;
  const int grow = g * 32 + row;
  const int hc   = b * 16 + jd * 2;

  float ccx = c0[(size_t)grow * HH + hc];
  float ccy = c0[(size_t)grow * HH + hc + 1];
  const float bx0 = bias[0 * HH + hc], by0 = bias[0 * HH + hc + 1];
  const float bx1 = bias[1 * HH + hc], by1 = bias[1 * HH + hc + 1];
  const float bx2 = bias[2 * HH + hc], by2 = bias[2 * HH + hc + 1];
  const float bx3 = bias[3 * HH + hc], by3 = bias[3 * HH + hc + 1];

  // int8 publish byte-offset within group slot: [ci][sub][row][k]
  const size_t puboff = (size_t)(hc >> 4) * 512 + (size_t)((hc >> 3) & 1) * 256
                      + (size_t)row * 8 + (size_t)(hc & 7);

  __syncthreads();   // Wl ready

#pragma unroll 1
  for (int t = 0; t < TT; ++t) {
    // ---- prefetch gx (4x4B) + resets before the poll ----
    const unsigned short* gp = gx + ((size_t)t * BB + grow) * 4096 + hc;
    const unsigned int gx0 = *(const unsigned int*)(gp);
    const unsigned int gx1 = *(const unsigned int*)(gp + 1024);
    const unsigned int gx2 = *(const unsigned int*)(gp + 2048);
    const unsigned int gx3 = *(const unsigned int*)(gp + 3072);
    bool rc, rn = false;
    if (byteMode) {
      rc = resetsB[t * BB + grow] != 0;
      if (t + 1 < TT) rn = resetsB[(t + 1) * BB + grow] != 0;
    } else {
      rc = resetsI[t * BB + grow] != 0;
      if (t + 1 < TT) rn = resetsI[(t + 1) * BB + grow] != 0;
    }

    // ---- poll own group's 64 producer flags (relaxed agent loads) ----
    {
      const unsigned int need = (unsigned int)(t + 1);
      const unsigned int* fp = flags + g * 64;
      while (true) {
        unsigned int v = __hip_atomic_load(&fp[ln], __ATOMIC_RELAXED,
                                           __HIP_MEMORY_SCOPE_AGENT);
        if (__all(v >= need)) break;
        __builtin_amdgcn_s_sleep(2);
      }
    }
    // gx/reset prefetches stay in flight; counted vmcnt below is E-robust.
    asm volatile("" ::: "memory");
    __builtin_amdgcn_sched_barrier(0);

    // ---- h MFMA phase ----
    f32x16 ac0 = {0.f,0.f,0.f,0.f, 0.f,0.f,0.f,0.f, 0.f,0.f,0.f,0.f, 0.f,0.f,0.f,0.f};
    f32x16 ac1 = {0.f,0.f,0.f,0.f, 0.f,0.f,0.f,0.f, 0.f,0.f,0.f,0.f, 0.f,0.f,0.f,0.f};
    if (t == 0) {
      // bf16 h0 path (no quantization)
      const char* hbB16 = (const char*)hbufB16
                        + (size_t)g * 65536 + (size_t)kc0 * 1024
                        + (size_t)lhi * 512 + (size_t)l31 * 16;
      bf8 hb16[16];
      HI3(0);  HI3(1);  HI3(2);  HI3(3);  HI3(4);  HI3(5);  HI3(6);  HI3(7);
      HI3(8);  HI3(9);  HI3(10); HI3(11); HI3(12); HI3(13); HI3(14); HI3(15);
      bf8 cb0 = BRD3(kc0, 0), cb1 = BRD3(kc0, 1);
      HC3(0, 15);  HC3(1, 14);  HC3(2, 13);  HC3(3, 12);
      HC3(4, 11);  HC3(5, 10);  HC3(6, 9);   HC3(7, 8);
      HC3(8, 7);   HC3(9, 6);   HC3(10, 5);  HC3(11, 4);
      HC3(12, 3);  HC3(13, 2);  HC3(14, 1);  HC3(15, 0);
    } else {
      // int8 path (half coherent traffic)
      const char* hbQ = (const char*)hbufQ + (size_t)(t & 1) * HSLOTQ
                      + (size_t)g * 32768 + (size_t)kc0 * 512
                      + (size_t)lhi * 256 + (size_t)l31 * 8;
      u32x2 haq[16];
      HIQ(0);  HIQ(1);  HIQ(2);  HIQ(3);  HIQ(4);  HIQ(5);  HIQ(6);  HIQ(7);
      HIQ(8);  HIQ(9);  HIQ(10); HIQ(11); HIQ(12); HIQ(13); HIQ(14); HIQ(15);
      bf8 cb0 = BRD3(kc0, 0), cb1 = BRD3(kc0, 1);
      HCQ(0, 15);  HCQ(1, 14);  HCQ(2, 13);  HCQ(3, 12);
      HCQ(4, 11);  HCQ(5, 10);  HCQ(6, 9);   HCQ(7, 8);
      HCQ(8, 7);   HCQ(9, 6);   HCQ(10, 5);  HCQ(11, 4);
      HCQ(12, 3);  HCQ(13, 2);  HCQ(14, 1);  HCQ(15, 0);
    }

    // ---- 4-way K combine: waves 1..3 dump to TMP; wq0 accumulates + writes GL ----
    if (wq > 0) {
      char* tp = sm + TMP_OFF + (wq - 1) * 8192 + ln * 16;
#pragma unroll
      for (int qd = 0; qd < 4; ++qd) {
        f32x4 v0 = {ac0[qd*4+0], ac0[qd*4+1], ac0[qd*4+2], ac0[qd*4+3]};
        f32x4 v1 = {ac1[qd*4+0], ac1[qd*4+1], ac1[qd*4+2], ac1[qd*4+3]};
        *(f32x4*)(tp + qd * 1024)        = v0;
        *(f32x4*)(tp + 4096 + qd * 1024) = v1;
      }
    }
    __syncthreads();   // TMP dumped
    if (wq == 0) {
#pragma unroll
      for (int s = 0; s < 3; ++s) {
        const char* tp = sm + TMP_OFF + s * 8192 + ln * 16;
#pragma unroll
        for (int qd = 0; qd < 4; ++qd) {
          f32x4 v0 = *(const f32x4*)(tp + qd * 1024);
          f32x4 v1 = *(const f32x4*)(tp + 4096 + qd * 1024);
          ac0[qd*4+0] += v0[0]; ac0[qd*4+1] += v0[1];
          ac0[qd*4+2] += v0[2]; ac0[qd*4+3] += v0[3];
          ac1[qd*4+0] += v1[0]; ac1[qd*4+1] += v1[1];
          ac1[qd*4+2] += v1[2]; ac1[qd*4+3] += v1[3];
        }
      }
      // D layout 32x32: col = lane&31, row = (reg&3) + 8*(reg>>2) + 4*(lane>>5)
#pragma unroll
      for (int r = 0; r < 16; ++r) {
        const int rowl = (r & 3) + 8 * (r >> 2) + 4 * lhi;
        TG[rowl * 66 + l31]      = ac0[r];
        TG[rowl * 66 + 32 + l31] = ac1[r];
      }
    }
    __syncthreads();   // GL ready

    // ---- elementwise LSTM: 2 cells per thread; h-sum scaled by 1/127 (t>0) ----
    const float sinv = (t == 0) ? 1.0f : (1.0f / 127.0f);
    const float* GLr = TG + row * 66;
    const int hl = jd * 2;
    const float i0 = GLr[ 0 + hl]     * sinv + bf2f((unsigned short)(gx0 & 0xffff)) + bx0;
    const float i1 = GLr[ 0 + hl + 1] * sinv + bf2f((unsigned short)(gx0 >> 16))    + by0;
    const float f0 = GLr[16 + hl]     * sinv + bf2f((unsigned short)(gx1 & 0xffff)) + bx1;
    const float f1 = GLr[16 + hl + 1] * sinv + bf2f((unsigned short)(gx1 >> 16))    + by1;
    const float g0 = GLr[32 + hl]     * sinv + bf2f((unsigned short)(gx2 & 0xffff)) + bx2;
    const float g1 = GLr[32 + hl + 1] * sinv + bf2f((unsigned short)(gx2 >> 16))    + by2;
    const float o0 = GLr[48 + hl]     * sinv + bf2f((unsigned short)(gx3 & 0xffff)) + bx3;
    const float o1 = GLr[48 + hl + 1] * sinv + bf2f((unsigned short)(gx3 >> 16))    + by3;
    const float cox = rc ? 0.f : ccx;
    const float coy = rc ? 0.f : ccy;
    const float ncx = sigm(f0) * cox + sigm(i0) * ftanh(g0);
    const float ncy = sigm(f1) * coy + sigm(i1) * ftanh(g1);
    const float nhx = sigm(o0) * ftanh(ncx);
    const float nhy = sigm(o1) * ftanh(ncy);
    ccx = ncx; ccy = ncy;

    // ---- publish h as int8 (2B coherent store) + flag, then out stores ----
    if (t + 1 < TT) {
      const float hx = rn ? 0.f : nhx * 127.0f;
      const float hy = rn ? 0.f : nhy * 127.0f;
      const int qx = (int)__builtin_rintf(hx);
      const int qy = (int)__builtin_rintf(hy);
      const unsigned int hp = (unsigned int)((qx & 0xff) | ((qy & 0xff) << 8));
      char* dst = (char*)hbufQ + (size_t)((t + 1) & 1) * HSLOTQ
                + (size_t)g * 32768 + puboff;
      asm volatile("global_store_short %0, %1, off sc0 sc1" :: "v"(dst), "v"(hp) : "memory");
      asm volatile("s_waitcnt vmcnt(0)" ::: "memory");
      __syncthreads();
      if (tid == 0) {
        unsigned int* fp = flags + bid;
        const unsigned int val = (unsigned int)(t + 2);
        asm volatile("global_store_dword %0, %1, off sc0 sc1" :: "v"(fp), "v"(val) : "memory");
      }
      float* op = out + (size_t)t * BB * HH + (size_t)grow * HH + hc;
      op[0] = nhx; op[1] = nhy;
    } else {
      float* op = out + (size_t)t * BB * HH + (size_t)grow * HH + hc;
      op[0] = nhx; op[1] = nhy;
      float* hp2 = out + (size_t)TT * BB * HH + (size_t)grow * HH + hc;
      hp2[0] = nhx; hp2[1] = nhy;
      float* cp2 = out + (size_t)TT * BB * HH + (size_t)BB * HH + (size_t)grow * HH + hc;
      cp2[0] = ncx; cp2[1] = ncy;
    }
  }
}

// ---------------- launch ----------------

extern "C" void kernel_launch(void* const* d_in, const int* in_sizes, int n_in,
                              void* d_out, int out_size, void* d_ws, size_t ws_size,
                              hipStream_t stream) {
  const float* obs  = (const float*)d_in[0];
  const void*  rst  = d_in[1];
  const float* h0   = (const float*)d_in[2];
  const float* c0   = (const float*)d_in[3];
  const float* Wx   = (const float*)d_in[4];
  const float* Wh   = (const float*)d_in[5];
  const float* bias = (const float*)d_in[6];
  float* out = (float*)d_out;

  char* ws = (char*)d_ws;
  const size_t WP_OFF     = 0;                                   // 16 MiB
  const size_t FLAGS_OFF  = ((size_t)16 << 20) + ((size_t)512 << 10);
  const size_t HBUFB_OFF  = (size_t)17 << 20;                    // 256 KiB (bf16 h0)
  const size_t HBUFQ_OFF  = ((size_t)17 << 20) + ((size_t)512 << 10); // 256 KiB (int8, 2 slots)
  const size_t OBSBF_OFF  = (size_t)24 << 20;                    // 128 MiB
  const size_t GX_OFF     = OBSBF_OFF + ((size_t)128 << 20);     // 512 MiB

  unsigned short* Wp      = (unsigned short*)(ws + WP_OFF);
  unsigned int*   flags   = (unsigned int*)(ws + FLAGS_OFF);
  int*        flagmode    = (int*)(flags + 1024);
  unsigned short* hbufB16 = (unsigned short*)(ws + HBUFB_OFF);
  unsigned char*  hbufQ   = (unsigned char*)(ws + HBUFQ_OFF);
  unsigned short* obsbf   = (unsigned short*)(ws + OBSBF_OFF);
  unsigned short* gxp     = (unsigned short*)(ws + GX_OFF);

  const unsigned char* rB = (const unsigned char*)rst;
  const int* rI = (const int*)rst;

  k_detect<<<1, 256, 0, stream>>>((const unsigned int*)rst, flagmode, flags);
  k_pack<<<dim3((KT / 64) * (NG / 64)), dim3(256), 0, stream>>>(Wx, Wh, Wp);
  k_initB3<<<dim3((BB * HH) / 256), dim3(256), 0, stream>>>(h0, rB, rI, flagmode, hbufB16);
  k_cvt<<<dim3(2048), dim3(256), 0, stream>>>(obs, obsbf);
  hipFuncSetAttribute((const void*)k_gemm,
                      hipFuncAttributeMaxDynamicSharedMemorySize, GEMM_SMEM);
  k_gemm<<<dim3((TT * BB / 128) * (NG / 128)), dim3(256), GEMM_SMEM, stream>>>(
      obsbf, Wp, gxp);

  hipFuncSetAttribute((const void*)k_scanh,
                      hipFuncAttributeMaxDynamicSharedMemorySize, SCANH_SMEM);
  void* args3[] = { (void*)&rB, (void*)&rI, (void*)&c0, (void*)&bias, (void*)&Wp,
                    (void*)&gxp, (void*)&hbufB16, (void*)&hbufQ, (void*)&flags,
                    (void*)&flagmode, (void*)&out };
  hipLaunchCooperativeKernel((const void*)k_scanh, dim3(256), dim3(256), args3,
                             SCANH_SMEM, stream);
}

// Round 14
// 2666.092 us; speedup vs baseline: 2.3507x; 1.0517x over previous
//
#include <hip/hip_runtime.h>
#include <hip/hip_bf16.h>

// Problem dims
#define TT 512
#define BB 128
#define DD 1024
#define HH 1024
#define NG 4096    // 4*HH gate columns
#define KT 2048    // DD+HH

using bf8    = __attribute__((ext_vector_type(8))) short;   // 8 bf16 bit patterns
using f32x4  = __attribute__((ext_vector_type(4))) float;
using f32x16 = __attribute__((ext_vector_type(16))) float;

__device__ __forceinline__ unsigned short f2bf(float f) {
  unsigned int u = __builtin_bit_cast(unsigned int, f);
  u += 0x7fffu + ((u >> 16) & 1u);   // RNE
  return (unsigned short)(u >> 16);
}
__device__ __forceinline__ float bf2f(unsigned short u) {
  unsigned int x = ((unsigned int)u) << 16;
  return __builtin_bit_cast(float, x);
}
__device__ __forceinline__ float sigm(float x) { return 1.0f / (1.0f + __expf(-x)); }
__device__ __forceinline__ float ftanh(float x) {
  float e = __expf(2.0f * x);
  return 1.0f - 2.0f / (e + 1.0f);
}

// ---------------- prep kernels ----------------

__global__ void k_detect(const unsigned int* __restrict__ rw, int* __restrict__ flagmode,
                         unsigned int* __restrict__ flags) {
  __shared__ int any;
  if (threadIdx.x == 0) any = 0;
  __syncthreads();
  int loc = 0;
  for (int i = threadIdx.x; i < (TT * BB) / 4; i += blockDim.x)
    if (rw[i] > 1u) loc = 1;
  if (loc) atomicOr(&any, 1);
  __syncthreads();
  if (threadIdx.x == 0) *flagmode = any;
  flags[threadIdx.x] = 1u;   // all 256 producer flags: h-input for step 0 ready
}

// Pack W = [Wx; Wh] (KT x NG, f32 row-major) into Wp[n][k] bf16 (N-major).
__global__ void k_pack(const float* __restrict__ Wx, const float* __restrict__ Wh,
                       unsigned short* __restrict__ Wp) {
  __shared__ unsigned short tile[64][65];
  const int kt = blockIdx.x & 31;
  const int nt = blockIdx.x >> 5;
  const int k0 = kt * 64, n0 = nt * 64;
  const int t = threadIdx.x;
  {
    const int kl = t >> 2;
    const int nl = (t & 3) * 16;
    const int kg = k0 + kl;
    const float* src = (kg < DD) ? (Wx + (size_t)kg * NG + n0 + nl)
                                 : (Wh + (size_t)(kg - DD) * NG + n0 + nl);
#pragma unroll
    for (int j = 0; j < 16; ++j) tile[kl][nl + j] = f2bf(src[j]);
  }
  __syncthreads();
  {
    const int nl = t >> 2;
    const int kl = (t & 3) * 16;
    unsigned short* dst = Wp + (size_t)(n0 + nl) * KT + k0 + kl;
#pragma unroll
    for (int j = 0; j < 16; ++j) dst[j] = tile[kl + j][nl];
  }
}

// staged-layout hbufB init: per group [ci 0..63][lhi 0..1][row32][8]
__global__ void k_initB3(const float* __restrict__ h0, const unsigned char* __restrict__ rB,
                         const int* __restrict__ rI, const int* __restrict__ flagmode,
                         unsigned short* __restrict__ hbufB) {
  const int i = blockIdx.x * 256 + threadIdx.x;
  if (i >= BB * HH) return;
  const int row = i >> 10, hcol = i & 1023;
  const bool r = (*flagmode) ? (rB[row] != 0) : (rI[row] != 0);
  const unsigned short val = r ? (unsigned short)0 : f2bf(h0[i]);
  const int g = row >> 5, rl = row & 31;
  const size_t e = (size_t)g * 32768 + (size_t)(hcol >> 4) * 512
                 + (size_t)((hcol >> 3) & 1) * 256 + (size_t)rl * 8 + (hcol & 7);
  hbufB[e] = val;
}

// obs f32 -> bf16
__global__ void k_cvt(const float* __restrict__ src, unsigned short* __restrict__ dst) {
  size_t i = ((size_t)blockIdx.x * 256 + threadIdx.x) * 8;
  const size_t stride = (size_t)2048 * 256 * 8;
  for (; i < (size_t)TT * BB * DD; i += stride) {
    f32x4 a = *(const f32x4*)(src + i);
    f32x4 c = *(const f32x4*)(src + i + 4);
    uint4 cv;
    asm("v_cvt_pk_bf16_f32 %0, %1, %2" : "=v"(cv.x) : "v"(a[0]), "v"(a[1]));
    asm("v_cvt_pk_bf16_f32 %0, %1, %2" : "=v"(cv.y) : "v"(a[2]), "v"(a[3]));
    asm("v_cvt_pk_bf16_f32 %0, %1, %2" : "=v"(cv.z) : "v"(c[0]), "v"(c[1]));
    asm("v_cvt_pk_bf16_f32 %0, %1, %2" : "=v"(cv.w) : "v"(c[2]), "v"(c[3]));
    *(bf8*)(dst + i) = __builtin_bit_cast(bf8, cv);
  }
}

// ---------------- gx = obs_bf @ Wx  (round-8 proven form, no swizzle) ----------------
#define GEMM_SMEM 69632

__global__ void __launch_bounds__(256)
k_gemm(const unsigned short* __restrict__ A, const unsigned short* __restrict__ Bw,
       unsigned short* __restrict__ C) {
  extern __shared__ char gsm[];
  const int tid = threadIdx.x;
  const int w = tid >> 6, l = tid & 63;
  const int l15 = l & 15, lh4 = l >> 4;
  const int wm2 = w >> 1, wn2 = w & 1;
  const int mt = blockIdx.x >> 5, nt = blockIdx.x & 31;
  const size_t m0 = (size_t)mt * 128, n0 = (size_t)nt * 128;

  f32x4 acc[4][4] = {};

  const int srow = l >> 3;
  const int schunk = (l & 7) ^ srow;

  const unsigned short* Ag[4];
  const unsigned short* Bg[4];
#pragma unroll
  for (int i = 0; i < 4; ++i) {
    const int r = w * 32 + i * 8 + srow;
    Ag[i] = A + (m0 + r) * 1024 + schunk * 8;
    Bg[i] = Bw + (n0 + r) * 2048 + schunk * 8;
  }

#define GSTAGE(BUF, KS) do {                                                        \
    const size_t ko_ = (size_t)(KS) * 64;                                           \
    char* base_ = gsm + (BUF) * 32768;                                              \
    _Pragma("unroll")                                                               \
    for (int i_ = 0; i_ < 4; ++i_) {                                                \
      __builtin_amdgcn_global_load_lds(                                             \
        (const __attribute__((address_space(1))) unsigned int*)(Ag[i_] + ko_),      \
        (__attribute__((address_space(3))) unsigned int*)(base_ + (w*32 + i_*8)*128), \
        16, 0, 0);                                                                  \
      __builtin_amdgcn_global_load_lds(                                             \
        (const __attribute__((address_space(1))) unsigned int*)(Bg[i_] + ko_),      \
        (__attribute__((address_space(3))) unsigned int*)(base_ + 16384 + (w*32 + i_*8)*128), \
        16, 0, 0);                                                                  \
    }                                                                               \
  } while (0)

#define GCOMP(BUF) do {                                                             \
    const char* bA_ = gsm + (BUF) * 32768;                                          \
    const char* bB_ = bA_ + 16384;                                                  \
    _Pragma("unroll")                                                               \
    for (int kk_ = 0; kk_ < 2; ++kk_) {                                             \
      bf8 af_[4], bf_[4];                                                           \
      _Pragma("unroll")                                                             \
      for (int mi_ = 0; mi_ < 4; ++mi_) {                                           \
        const int r_ = wm2 * 64 + mi_ * 16 + l15;                                   \
        af_[mi_] = *(const bf8*)(bA_ + r_ * 128 + ((kk_*64 + lh4*16) ^ ((r_ & 7) << 4))); \
      }                                                                             \
      _Pragma("unroll")                                                             \
      for (int ni_ = 0; ni_ < 4; ++ni_) {                                           \
        const int r_ = wn2 * 64 + ni_ * 16 + l15;                                   \
        bf_[ni_] = *(const bf8*)(bB_ + r_ * 128 + ((kk_*64 + lh4*16) ^ ((r_ & 7) << 4))); \
      }                                                                             \
      _Pragma("unroll")                                                             \
      for (int mi_ = 0; mi_ < 4; ++mi_)                                             \
        _Pragma("unroll")                                                           \
        for (int ni_ = 0; ni_ < 4; ++ni_)                                           \
          acc[mi_][ni_] = __builtin_amdgcn_mfma_f32_16x16x32_bf16(                  \
              af_[mi_], bf_[ni_], acc[mi_][ni_], 0, 0, 0);                          \
    }                                                                               \
  } while (0)

  GSTAGE(0, 0);
  asm volatile("s_waitcnt vmcnt(0)" ::: "memory");
  __syncthreads();
#pragma unroll 1
  for (int ks = 0; ks < 16; ++ks) {
    if (ks < 15) GSTAGE((ks + 1) & 1, ks + 1);
    GCOMP(ks & 1);
    if (ks < 15) {
      asm volatile("s_waitcnt vmcnt(0)" ::: "memory");
      __syncthreads();
    }
  }

  __syncthreads();
  float* ct = (float*)(gsm + w * 17408);   // [64][68] f32
#pragma unroll
  for (int mi = 0; mi < 4; ++mi)
#pragma unroll
    for (int ni = 0; ni < 4; ++ni)
#pragma unroll
      for (int q = 0; q < 4; ++q)
        ct[(mi * 16 + lh4 * 4 + q) * 68 + ni * 16 + l15] = acc[mi][ni][q];
#pragma unroll
  for (int i = 0; i < 8; ++i) {
    const int row = i * 8 + (l >> 3);
    const int c8 = (l & 7) * 8;
    f32x4 v0 = *(const f32x4*)(ct + row * 68 + c8);
    f32x4 v1 = *(const f32x4*)(ct + row * 68 + c8 + 4);
    uint4 cv;
    asm("v_cvt_pk_bf16_f32 %0, %1, %2" : "=v"(cv.x) : "v"(v0[0]), "v"(v0[1]));
    asm("v_cvt_pk_bf16_f32 %0, %1, %2" : "=v"(cv.y) : "v"(v0[2]), "v"(v0[3]));
    asm("v_cvt_pk_bf16_f32 %0, %1, %2" : "=v"(cv.z) : "v"(v1[0]), "v"(v1[1]));
    asm("v_cvt_pk_bf16_f32 %0, %1, %2" : "=v"(cv.w) : "v"(v1[2]), "v"(v1[3]));
    *(bf8*)(C + (m0 + wm2 * 64 + row) * 4096 + n0 + wn2 * 64 + c8) =
        __builtin_bit_cast(bf8, cv);
  }
#undef GSTAGE
#undef GCOMP
}

// ---------------- serial h-scan v8: bf16 h, per-wave narrow poll, 2-barrier combine ----------------
// LDS: Wl [k8 0..127][c 0..63][16B] @0 (131072); TMP 3x8KB @131072; GL [32][66] f32 aliases
#define SCANH_SMEM 155648
#define TMP_OFF 131072
#define HSLOT3 262144   // 4 groups * 64KB per hbufB slot

#define HI3(I) asm volatile("global_load_dwordx4 %0, %1, off sc0 sc1" \
    : "=v"(ha[I]) : "v"(hbB + (I) * 1024) : "memory")

// B fragment: global k16-chunk CI, col-tile CN: Wl[(CI*2+lhi)][CN*32+l31]
#define BRD3(CI, CN) (*(const bf8*)(sm + \
    (size_t)((((CI) * 2 + lhi) * 64 + (CN) * 32 + l31)) * 16))

// Counted vmcnt is E-robust: h-loads are the newest 16 outstanding vmem ops.
#define HC3(CI, VM) do {                                                  \
    bf8 nb0, nb1;                                                         \
    if ((CI) < 15) { nb0 = BRD3(kc0 + (CI) + 1, 0); nb1 = BRD3(kc0 + (CI) + 1, 1); } \
    asm volatile("s_waitcnt vmcnt(" #VM ")" ::: "memory");                \
    __builtin_amdgcn_sched_barrier(0);                                    \
    ac0 = __builtin_amdgcn_mfma_f32_32x32x16_bf16(ha[CI], cb0, ac0, 0, 0, 0); \
    ac1 = __builtin_amdgcn_mfma_f32_32x32x16_bf16(ha[CI], cb1, ac1, 0, 0, 0); \
    cb0 = nb0; cb1 = nb1;                                                 \
  } while (0)

__global__ void __launch_bounds__(256)
k_scanh(const unsigned char* __restrict__ resetsB, const int* __restrict__ resetsI,
        const float* __restrict__ c0, const float* __restrict__ bias,
        const unsigned short* __restrict__ Wp, const unsigned short* __restrict__ gx,
        unsigned short* __restrict__ hbufB, unsigned int* __restrict__ flags,
        const int* __restrict__ flagmode, float* __restrict__ out) {
  extern __shared__ char sm[];
  float* TG = (float*)(sm + TMP_OFF);

  const int tid = threadIdx.x;
  const int wq  = tid >> 6;
  const int ln  = tid & 63;
  const int l31 = ln & 31;
  const int lhi = ln >> 5;
  const int kc0 = wq * 16;
  const int bid = blockIdx.x;
  const int g   = bid >> 6;        // batch group 0..3 (rows 32g..32g+31)
  const int b   = bid & 63;        // 16 h-cols per block
  const int byteMode = *flagmode;

  // ---- Wl slice -> LDS (once): [k8][c][8], c = gate*16 + hcl ----
  {
    const int c = tid >> 2, seg = tid & 3;
    const int n = (c >> 4) * 1024 + b * 16 + (c & 15);
    const unsigned short* src = Wp + (size_t)n * KT + 1024;
#pragma unroll 8
    for (int i = 0; i < 32; ++i) {
      const int k8 = seg * 32 + i;
      bf8 v = *(const bf8*)(src + k8 * 8);
      *(bf8*)(sm + ((size_t)k8 * 64 + c) * 16) = v;
    }
  }

  const int row  = tid >> 3;           // 0..31
  const int jd   = tid & 7;
  const int grow = g * 32 + row;
  const int hc   = b * 16 + jd * 2;

  float ccx = c0[(size_t)grow * HH + hc];
  float ccy = c0[(size_t)grow * HH + hc + 1];
  const float bx0 = bias[0 * HH + hc], by0 = bias[0 * HH + hc + 1];
  const float bx1 = bias[1 * HH + hc], by1 = bias[1 * HH + hc + 1];
  const float bx2 = bias[2 * HH + hc], by2 = bias[2 * HH + hc + 1];
  const float bx3 = bias[3 * HH + hc], by3 = bias[3 * HH + hc + 1];

  const size_t puboff = (size_t)(hc >> 4) * 1024 + (size_t)((hc >> 3) & 1) * 512
                      + (size_t)row * 16 + (size_t)(hc & 7) * 2;

  // per-wave poll set: wave wq reads h-cols [wq*256, wq*256+256) produced by
  // group blocks g*64 + wq*16 .. +15 (16 flags; lanes repeat mod 16)
  const unsigned int* pollp = flags + g * 64 + wq * 16 + (ln & 15);

  __syncthreads();   // Wl ready

#pragma unroll 1
  for (int t = 0; t < TT; ++t) {
    // ---- prefetch gx (4x4B) + resets before the poll ----
    const unsigned short* gp = gx + ((size_t)t * BB + grow) * 4096 + hc;
    const unsigned int gx0 = *(const unsigned int*)(gp);
    const unsigned int gx1 = *(const unsigned int*)(gp + 1024);
    const unsigned int gx2 = *(const unsigned int*)(gp + 2048);
    const unsigned int gx3 = *(const unsigned int*)(gp + 3072);
    bool rc, rn = false;
    if (byteMode) {
      rc = resetsB[t * BB + grow] != 0;
      if (t + 1 < TT) rn = resetsB[(t + 1) * BB + grow] != 0;
    } else {
      rc = resetsI[t * BB + grow] != 0;
      if (t + 1 < TT) rn = resetsI[(t + 1) * BB + grow] != 0;
    }

    // ---- per-wave poll: only this K-quarter's 16 producer blocks ----
    {
      const unsigned int need = (unsigned int)(t + 1);
      while (true) {
        unsigned int v = __hip_atomic_load(pollp, __ATOMIC_RELAXED,
                                           __HIP_MEMORY_SCOPE_AGENT);
        if (__all(v >= need)) break;
        __builtin_amdgcn_s_sleep(2);
      }
    }
    // gx/reset prefetches stay in flight; HC3's counted vmcnt is E-robust.
    asm volatile("" ::: "memory");
    __builtin_amdgcn_sched_barrier(0);

    // ---- h MFMA phase: 16 staged A-loads, counted vmcnt ----
    f32x16 ac0 = {0.f,0.f,0.f,0.f, 0.f,0.f,0.f,0.f, 0.f,0.f,0.f,0.f, 0.f,0.f,0.f,0.f};
    f32x16 ac1 = {0.f,0.f,0.f,0.f, 0.f,0.f,0.f,0.f, 0.f,0.f,0.f,0.f, 0.f,0.f,0.f,0.f};
    {
      const char* hbB = (const char*)hbufB + (size_t)(t & 1) * HSLOT3
                      + (size_t)g * 65536 + (size_t)kc0 * 1024
                      + (size_t)lhi * 512 + (size_t)l31 * 16;
      bf8 ha[16];
      HI3(0);  HI3(1);  HI3(2);  HI3(3);  HI3(4);  HI3(5);  HI3(6);  HI3(7);
      HI3(8);  HI3(9);  HI3(10); HI3(11); HI3(12); HI3(13); HI3(14); HI3(15);
      bf8 cb0 = BRD3(kc0, 0), cb1 = BRD3(kc0, 1);
      HC3(0, 15);  HC3(1, 14);  HC3(2, 13);  HC3(3, 12);
      HC3(4, 11);  HC3(5, 10);  HC3(6, 9);   HC3(7, 8);
      HC3(8, 7);   HC3(9, 6);   HC3(10, 5);  HC3(11, 4);
      HC3(12, 3);  HC3(13, 2);  HC3(14, 1);  HC3(15, 0);
    }

    // ---- 4-way K combine: waves 1..3 dump to TMP; wq0 accumulates + writes GL
    //      (wq0's TMP reads -> GL writes are same-wave LDS-ordered: 2 barriers)
    if (wq > 0) {
      char* tp = sm + TMP_OFF + (wq - 1) * 8192 + ln * 16;
#pragma unroll
      for (int qd = 0; qd < 4; ++qd) {
        f32x4 v0 = {ac0[qd*4+0], ac0[qd*4+1], ac0[qd*4+2], ac0[qd*4+3]};
        f32x4 v1 = {ac1[qd*4+0], ac1[qd*4+1], ac1[qd*4+2], ac1[qd*4+3]};
        *(f32x4*)(tp + qd * 1024)        = v0;
        *(f32x4*)(tp + 4096 + qd * 1024) = v1;
      }
    }
    __syncthreads();   // TMP dumped
    if (wq == 0) {
#pragma unroll
      for (int s = 0; s < 3; ++s) {
        const char* tp = sm + TMP_OFF + s * 8192 + ln * 16;
#pragma unroll
        for (int qd = 0; qd < 4; ++qd) {
          f32x4 v0 = *(const f32x4*)(tp + qd * 1024);
          f32x4 v1 = *(const f32x4*)(tp + 4096 + qd * 1024);
          ac0[qd*4+0] += v0[0]; ac0[qd*4+1] += v0[1];
          ac0[qd*4+2] += v0[2]; ac0[qd*4+3] += v0[3];
          ac1[qd*4+0] += v1[0]; ac1[qd*4+1] += v1[1];
          ac1[qd*4+2] += v1[2]; ac1[qd*4+3] += v1[3];
        }
      }
      // D layout 32x32: col = lane&31, row = (reg&3) + 8*(reg>>2) + 4*(lane>>5)
#pragma unroll
      for (int r = 0; r < 16; ++r) {
        const int rowl = (r & 3) + 8 * (r >> 2) + 4 * lhi;
        TG[rowl * 66 + l31]      = ac0[r];
        TG[rowl * 66 + 32 + l31] = ac1[r];
      }
    }
    __syncthreads();   // GL ready

    // ---- elementwise LSTM: 2 cells per thread ----
    const float* GLr = TG + row * 66;
    const int hl = jd * 2;
    const float i0 = GLr[ 0 + hl]     + bf2f((unsigned short)(gx0 & 0xffff)) + bx0;
    const float i1 = GLr[ 0 + hl + 1] + bf2f((unsigned short)(gx0 >> 16))    + by0;
    const float f0 = GLr[16 + hl]     + bf2f((unsigned short)(gx1 & 0xffff)) + bx1;
    const float f1 = GLr[16 + hl + 1] + bf2f((unsigned short)(gx1 >> 16))    + by1;
    const float g0 = GLr[32 + hl]     + bf2f((unsigned short)(gx2 & 0xffff)) + bx2;
    const float g1 = GLr[32 + hl + 1] + bf2f((unsigned short)(gx2 >> 16))    + by2;
    const float o0 = GLr[48 + hl]     + bf2f((unsigned short)(gx3 & 0xffff)) + bx3;
    const float o1 = GLr[48 + hl + 1] + bf2f((unsigned short)(gx3 >> 16))    + by3;
    const float cox = rc ? 0.f : ccx;
    const float coy = rc ? 0.f : ccy;
    const float ncx = sigm(f0) * cox + sigm(i0) * ftanh(g0);
    const float ncy = sigm(f1) * coy + sigm(i1) * ftanh(g1);
    const float nhx = sigm(o0) * ftanh(ncx);
    const float nhy = sigm(o1) * ftanh(ncy);
    ccx = ncx; ccy = ncy;

    // ---- publish h (4B coherent store) + flag, then out stores ----
    if (t + 1 < TT) {
      const float hx = rn ? 0.f : nhx, hy = rn ? 0.f : nhy;
      unsigned int hp;
      asm("v_cvt_pk_bf16_f32 %0, %1, %2" : "=v"(hp) : "v"(hx), "v"(hy));
      char* dst = (char*)hbufB + (size_t)((t + 1) & 1) * HSLOT3
                + (size_t)g * 65536 + puboff;
      asm volatile("global_store_dword %0, %1, off sc0 sc1" :: "v"(dst), "v"(hp) : "memory");
      asm volatile("s_waitcnt vmcnt(0)" ::: "memory");
      __syncthreads();
      if (tid == 0) {
        unsigned int* fp = flags + bid;
        const unsigned int val = (unsigned int)(t + 2);
        asm volatile("global_store_dword %0, %1, off sc0 sc1" :: "v"(fp), "v"(val) : "memory");
      }
      float* op = out + (size_t)t * BB * HH + (size_t)grow * HH + hc;
      op[0] = nhx; op[1] = nhy;
    } else {
      float* op = out + (size_t)t * BB * HH + (size_t)grow * HH + hc;
      op[0] = nhx; op[1] = nhy;
      float* hp2 = out + (size_t)TT * BB * HH + (size_t)grow * HH + hc;
      hp2[0] = nhx; hp2[1] = nhy;
      float* cp2 = out + (size_t)TT * BB * HH + (size_t)BB * HH + (size_t)grow * HH + hc;
      cp2[0] = ncx; cp2[1] = ncy;
    }
  }
}

// ---------------- launch ----------------

extern "C" void kernel_launch(void* const* d_in, const int* in_sizes, int n_in,
                              void* d_out, int out_size, void* d_ws, size_t ws_size,
                              hipStream_t stream) {
  const float* obs  = (const float*)d_in[0];
  const void*  rst  = d_in[1];
  const float* h0   = (const float*)d_in[2];
  const float* c0   = (const float*)d_in[3];
  const float* Wx   = (const float*)d_in[4];
  const float* Wh   = (const float*)d_in[5];
  const float* bias = (const float*)d_in[6];
  float* out = (float*)d_out;

  char* ws = (char*)d_ws;
  const size_t WP_OFF    = 0;                                   // 16 MiB
  const size_t FLAGS_OFF = ((size_t)16 << 20) + ((size_t)512 << 10);
  const size_t HBUFB_OFF = (size_t)17 << 20;                    // 0.5 MiB (staged layout)
  const size_t OBSBF_OFF = (size_t)24 << 20;                    // 128 MiB
  const size_t GX_OFF    = OBSBF_OFF + ((size_t)128 << 20);     // 512 MiB

  unsigned short* Wp    = (unsigned short*)(ws + WP_OFF);
  unsigned int*   flags = (unsigned int*)(ws + FLAGS_OFF);
  int*        flagmode  = (int*)(flags + 1024);
  unsigned short* hbufB = (unsigned short*)(ws + HBUFB_OFF);
  unsigned short* obsbf = (unsigned short*)(ws + OBSBF_OFF);
  unsigned short* gxp   = (unsigned short*)(ws + GX_OFF);

  const unsigned char* rB = (const unsigned char*)rst;
  const int* rI = (const int*)rst;

  k_detect<<<1, 256, 0, stream>>>((const unsigned int*)rst, flagmode, flags);
  k_pack<<<dim3((KT / 64) * (NG / 64)), dim3(256), 0, stream>>>(Wx, Wh, Wp);
  k_initB3<<<dim3((BB * HH) / 256), dim3(256), 0, stream>>>(h0, rB, rI, flagmode, hbufB);
  k_cvt<<<dim3(2048), dim3(256), 0, stream>>>(obs, obsbf);
  hipFuncSetAttribute((const void*)k_gemm,
                      hipFuncAttributeMaxDynamicSharedMemorySize, GEMM_SMEM);
  k_gemm<<<dim3((TT * BB / 128) * (NG / 128)), dim3(256), GEMM_SMEM, stream>>>(
      obsbf, Wp, gxp);

  hipFuncSetAttribute((const void*)k_scanh,
                      hipFuncAttributeMaxDynamicSharedMemorySize, SCANH_SMEM);
  void* args3[] = { (void*)&rB, (void*)&rI, (void*)&c0, (void*)&bias, (void*)&Wp,
                    (void*)&gxp, (void*)&hbufB, (void*)&flags, (void*)&flagmode,
                    (void*)&out };
  hipLaunchCooperativeKernel((const void*)k_scanh, dim3(256), dim3(256), args3,
                             SCANH_SMEM, stream);
}